// Round 3
// baseline (454.586 us; speedup 1.0000x reference)
//
#include <hip/hip_runtime.h>
#include <stdint.h>

// SO3Conv mapped per l to GEMM: C[(b,m),(g,v)] = A[(b,m),(u,f)] * B[(u,f),(g,v)]
//   A: pre-transposed x, bf16, row-major [M=1024d][K=64d], k = u*64+f
//   B: psi with both norms folded, bf16, B-operand layout Bt[n=(g*d+v)][k], rows padded to 128-mult with 0
// GEMM is LDS-free: fragments loaded directly from L2 (XCD swizzle keeps panels resident),
// double-buffered in registers, zero barriers in the K-loop.

typedef __bf16 bf16x8 __attribute__((ext_vector_type(8)));
typedef float floatx4 __attribute__((ext_vector_type(4)));

#define XROW 29120   // 64*455

__device__ __forceinline__ unsigned short f2bf(float f) {
  union { float f; unsigned int u; } c; c.f = f;
  unsigned int u = c.u;
  return (unsigned short)((u + 0x7FFFu + ((u >> 16) & 1u)) >> 16);
}
__device__ __forceinline__ unsigned int pack2(float a, float b) {
  return (unsigned int)f2bf(a) | ((unsigned int)f2bf(b) << 16);
}

__host__ __device__ constexpr int d_of(int L) { return 2 * L + 1; }
__host__ __device__ constexpr int off_of(int L) { int s = 0; for (int i = 0; i < L; ++i) s += d_of(i) * d_of(i); return s; }
__host__ __device__ constexpr size_t a_off(int L) { size_t s = 0; for (int i = 0; i < L; ++i) s += (size_t)65536 * d_of(i) * d_of(i); return s; }
__host__ __device__ constexpr size_t b_off(int L) { size_t s = a_off(7); for (int i = 0; i < L; ++i) s += (size_t)4096 * d_of(i) * (d_of(i) + 1); return s; }

// ---------------- Kernel 1 (fused): build B (blocks 0..447) + transpose x (blocks 448..1471) ----------------
__global__ __launch_bounds__(256) void prep(const float* __restrict__ x, const float* __restrict__ Dm,
                                            const float* __restrict__ w, unsigned short* __restrict__ ws) {
  __shared__ __align__(16) float smem[64 * 68 + 64 * 172];   // 60 KB
  const int tid = threadIdx.x;
  const int bid = blockIdx.x;

  if (bid < 448) {
    // ---- build B: psi[f,g,r] = sum_n w[f,g,n] D[n,off+r], norms folded, 4x4 register tiling ----
    float* wg = smem;              // [64][68]: wg[n][f]
    float* Dl = smem + 64 * 68;    // [64][172]: Dl[n][r], zero-padded
    const int g = bid & 63, l = bid >> 6;
    const int d = 2 * l + 1, d2 = d * d, K = 64 * d;
    int off = 0; size_t boff = a_off(7);
    for (int i = 0; i < l; ++i) { int dd = 2 * i + 1; off += dd * dd; boff += (size_t)4096 * dd * (dd + 1); }
    unsigned short* B = ws + boff;

    for (int t = tid; t < 4096; t += 256) {
      int n = t & 63, f = t >> 6;
      wg[n * 68 + f] = w[(size_t)f * 4096 + g * 64 + n];
    }
    for (int t = tid; t < 64 * 172; t += 256) {
      int n = t / 172, r = t - n * 172;
      Dl[t] = (r < d2) ? Dm[n * 455 + off + r] : 0.f;
    }
    __syncthreads();

    const float sl = 1.0f / (64.0f * sqrtf((float)d));
    const int RT = (d2 + 3) >> 2;
    for (int tt = tid; tt < 16 * RT; tt += 256) {
      const int ft = tt & 15, rt = tt >> 4;
      float acc[4][4] = {};
      for (int n = 0; n < 64; ++n) {
        floatx4 wv = *(const floatx4*)(wg + n * 68 + ft * 4);
        floatx4 dv = *(const floatx4*)(Dl + n * 172 + rt * 4);
#pragma unroll
        for (int a = 0; a < 4; ++a)
#pragma unroll
          for (int b2 = 0; b2 < 4; ++b2) acc[a][b2] += wv[a] * dv[b2];
      }
#pragma unroll
      for (int b2 = 0; b2 < 4; ++b2) {
        int r = rt * 4 + b2;
        if (r < d2) {
          int u = r / d, v = r - u * d;
          size_t base = (size_t)(g * d + v) * K + u * 64 + ft * 4;
#pragma unroll
          for (int a = 0; a < 4; ++a) B[base + a] = f2bf(acc[a][b2] * sl);
        }
      }
    }
    { // zero one pad row per g (rows 64d..64d+63 across the 64 g-blocks)
      int nn = 64 * d + g;
      for (int k = tid; k < K; k += 256) B[(size_t)nn * K + k] = 0;
    }
  } else {
    // ---- transpose x -> A (bf16), 2 phases of 32 f-rows, float4-coalesced staging ----
    float* xs = smem;   // 32 rows x 455 floats = 58.2 KB
    const int b = bid - 448;
    const float* xb = x + (size_t)b * XROW;
#pragma unroll
    for (int h = 0; h < 2; ++h) {
      const float4* src = (const float4*)(xb + h * 32 * 455);   // 14560 floats, 16B-aligned
      for (int t = tid; t < 3640; t += 256) ((float4*)xs)[t] = src[t];
      __syncthreads();
      size_t aoff = 0; int off = 0;
#pragma unroll
      for (int l = 0; l < 7; ++l) {
        const int d = 2 * l + 1, d2 = d * d;
        unsigned int* Au = (unsigned int*)(ws + aoff + (size_t)b * (64 * d2));
        for (int t = tid; t < 16 * d2; t += 256) {
          int f2 = t & 15, s = t >> 4;
          int u = s % d, m = s / d;
          int c = off + u * d + m;
          Au[s * 32 + h * 16 + f2] = pack2(xs[(2 * f2) * 455 + c], xs[(2 * f2 + 1) * 455 + c]);
        }
        off += d2; aoff += (size_t)1024 * 64 * d2;
      }
      __syncthreads();
    }
  }
}

// ---------------- Kernel 2: fused all-l LDS-free register GEMM ----------------
template <int L>
__device__ __forceinline__ void gemm_body(int local, const unsigned short* __restrict__ ws,
                                          float* __restrict__ out) {
  constexpr int d = 2 * L + 1;
  constexpr int K = 64 * d;
  constexpr int NT = (d + 1) / 2;          // N-tiles of 128 (N padded to 64*(d+1)); M-tiles = 8d
  constexpr int OFF = off_of(L);
  constexpr int ITERS = 2 * d;             // K / 32
  const unsigned short* A = ws + a_off(L);
  const unsigned short* B = ws + b_off(L);
  // XCD swizzle: all NT blocks sharing an A M-tile land on one XCD.
  const int x8 = local & 7, tt = local >> 3;
  const int mt = (tt / NT) * 8 + x8;
  const int nt = tt % NT;
  const int tid = threadIdx.x;
  const int w = tid >> 6, ln = tid & 63;
  const int wm = w >> 1, wn = w & 1;
  const int q = ln >> 4, r16 = ln & 15;

  // fragment base pointers: 16B contiguous per lane, full 64B lines per wave
  const unsigned short* ap = A + (size_t)(mt * 128 + wm * 64 + r16) * K + q * 8;
  const unsigned short* bp = B + (size_t)(nt * 128 + wn * 64 + r16) * K + q * 8;

  floatx4 acc[4][4] = {};
  bf16x8 ca[4], cb[4], na[4], nb[4];
#pragma unroll
  for (int i = 0; i < 4; ++i) {
    ca[i] = *(const bf16x8*)(ap + i * 16 * K);
    cb[i] = *(const bf16x8*)(bp + i * 16 * K);
  }
#pragma unroll 2
  for (int kt = 0; kt < ITERS - 1; ++kt) {
    const unsigned short* ap2 = ap + (kt + 1) * 32;
    const unsigned short* bp2 = bp + (kt + 1) * 32;
#pragma unroll
    for (int i = 0; i < 4; ++i) {
      na[i] = *(const bf16x8*)(ap2 + i * 16 * K);
      nb[i] = *(const bf16x8*)(bp2 + i * 16 * K);
    }
#pragma unroll
    for (int mi = 0; mi < 4; ++mi)
#pragma unroll
      for (int ni = 0; ni < 4; ++ni)
        acc[mi][ni] = __builtin_amdgcn_mfma_f32_16x16x32_bf16(ca[mi], cb[ni], acc[mi][ni], 0, 0, 0);
#pragma unroll
    for (int i = 0; i < 4; ++i) { ca[i] = na[i]; cb[i] = nb[i]; }
  }
#pragma unroll
  for (int mi = 0; mi < 4; ++mi)
#pragma unroll
    for (int ni = 0; ni < 4; ++ni)
      acc[mi][ni] = __builtin_amdgcn_mfma_f32_16x16x32_bf16(ca[mi], cb[ni], acc[mi][ni], 0, 0, 0);

  // epilogue: D[row=q*4+reg -> M=(b,m), col=r16 -> N=(g,v)]
#pragma unroll
  for (int ni = 0; ni < 4; ++ni) {
    int Cc = nt * 128 + wn * 64 + ni * 16 + r16;
    if (Cc < 64 * d) {
      int g = Cc / d, v = Cc - (Cc / d) * d;
#pragma unroll
      for (int mi = 0; mi < 4; ++mi) {
        int R0 = mt * 128 + wm * 64 + mi * 16 + q * 4;
#pragma unroll
        for (int reg = 0; reg < 4; ++reg) {
          int R = R0 + reg;
          int bb = R / d, m = R - (R / d) * d;
          out[(size_t)bb * XROW + g * 455 + OFF + v * d + m] = acc[mi][ni][reg];
        }
      }
    }
  }
}

__global__ __launch_bounds__(256) void gemm_all(const unsigned short* __restrict__ ws, float* __restrict__ out) {
  // blocks per l: 4d(d+1) = {8,48,120,224,360,528,728}; cum {8,56,176,400,760,1288,2016}
  int b0 = 2015 - (int)blockIdx.x;   // longest-l blocks dispatch first
  if      (b0 <    8) gemm_body<0>(b0,        ws, out);
  else if (b0 <   56) gemm_body<1>(b0 -    8, ws, out);
  else if (b0 <  176) gemm_body<2>(b0 -   56, ws, out);
  else if (b0 <  400) gemm_body<3>(b0 -  176, ws, out);
  else if (b0 <  760) gemm_body<4>(b0 -  400, ws, out);
  else if (b0 < 1288) gemm_body<5>(b0 -  760, ws, out);
  else                gemm_body<6>(b0 - 1288, ws, out);
}

extern "C" void kernel_launch(void* const* d_in, const int* in_sizes, int n_in,
                              void* d_out, int out_size, void* d_ws, size_t ws_size,
                              hipStream_t stream) {
  const float* x = (const float*)d_in[0];
  const float* D = (const float*)d_in[1];
  const float* w = (const float*)d_in[2];
  float* out = (float*)d_out;
  unsigned short* ws = (unsigned short*)d_ws;   // ~63.8 MB

  hipLaunchKernelGGL(prep, dim3(1472), dim3(256), 0, stream, x, D, w, ws);
  hipLaunchKernelGGL(gemm_all, dim3(2016), dim3(256), 0, stream, ws, out);
}